// Round 25
// baseline (70.854 us; speedup 1.0000x reference)
//
#include <hip/hip_runtime.h>
#include <math.h>

#define NFEAT 256
#define NROWS 65536
#define PCOUNT 4194304
#define PBLK 64                      // param-reduce blocks appended to pass1 grid
#define CH2 512                      // pass2 fallback chunks
#define RGRP 16                      // reduce_S c-groups
#define NSLOT 28                     // P1 slots per chunk per feature
#define F_EPS 5.9604645e-07f         // float32 eps * 5
#define F_LN2 0.69314718056f
#define DELTA_MAX 0.45f              // poly-validity gate on |0.1*rp|

#define FAST_LOG2(v) __builtin_log2f(v)   // v_log_f32
#define FAST_EXP2(v) __builtin_exp2f(v)   // v_exp_f32

constexpr double D_HALF_LOG2_2PIE = 0.5 * 2.8378770664093453 / 0.6931471805599453;
constexpr double D_LAMBDA_BITS = 13.287712379549449; // 2*log2(100)

__device__ inline double wave_reduce_add(double v) {
  for (int o = 32; o > 0; o >>= 1) v += __shfl_down(v, o, 64);
  return v;
}

// sum_k d^k/k! * m[k], k=0..5 (Horner)
__device__ inline double horner_exp(const double* m, double d) {
  double p = m[5] * (1.0 / 120.0);
  p = p * d + m[4] * (1.0 / 24.0);
  p = p * d + m[3] * (1.0 / 6.0);
  p = p * d + m[2] * 0.5;
  p = p * d + m[1];
  p = p * d + m[0];
  return p;
}

// ---------------------------------------------------------------------------
// Pass 1 (moment form, 512-thr dual-chunk blocks): thread = (f=tid&255,
// sub=tid>>8); sub handles chunk 2*blockIdx+sub. NO redundant work, no LDS.
// Empirical cross-round pattern: 512-thr blocks achieve 54-56% occupancy vs
// 20-24% for 256-thr blocks (same wave count, same VGPR) -- this round gives
// the LOWEST-busy kernel (moment form, 19us busy) the HIGH-residency launch
// shape. Moments: M_k = sum B*q^k, M2_k = sum B^2*q^k (k=0..5, pos/neg);
// B = exp2(center*u), q = u*ln2, u = log2(1+|x|). Reconstruction per-feature
// in f64 in k_pick (5th-order Taylor, same truncation as r13 -> absmax 0.0).
// Slots: 0..5 Mp, 6..11 Mp2, 12..17 Mn, 18..23 Mn2, 24 u2p, 25 u2a,
// 26 npos, 27 flag (1 = direct sums from exact general path).
// Blocks >= CHv/2: parameter tensor reduction (overlapped, memory-bound).
// ---------------------------------------------------------------------------
__global__ __launch_bounds__(512, 8) void k_pass1(
    const float* __restrict__ x, const float* __restrict__ lam1,
    const float* __restrict__ lam2, const float* __restrict__ rp,
    const float* __restrict__ params, float* __restrict__ P1,
    double* __restrict__ pSums, int CHv, int rpt)
{
  const int tid = threadIdx.x;
  const int nyj = CHv >> 1;            // YJ blocks

  if ((int)blockIdx.x >= nyj) {
    // ---- parameter tensor partial reduction ----
    __shared__ double lred[2][8];
    const int b = blockIdx.x - nyj;
    const float4* p4 = (const float4*)params;
    double s = 0.0, q = 0.0;
    for (int i = b * 512 + tid; i < PCOUNT / 4; i += PBLK * 512) {
      float4 v = p4[i];
      s += (double)v.x + (double)v.y + (double)v.z + (double)v.w;
      q += (double)v.x * v.x + (double)v.y * v.y
         + (double)v.z * v.z + (double)v.w * v.w;
    }
    s = wave_reduce_add(s); q = wave_reduce_add(q);
    const int w = tid >> 6;
    if ((tid & 63) == 0) { lred[0][w] = s; lred[1][w] = q; }
    __syncthreads();
    if (tid == 0) {
      double S = 0.0, Q = 0.0;
#pragma unroll
      for (int i = 0; i < 8; ++i) { S += lred[0][i]; Q += lred[1][i]; }
      atomicAdd(&pSums[0], S);
      atomicAdd(&pSums[1], Q);
    }
    return;
  }

  const int f = tid & 255;
  const int sub = tid >> 8;            // 0/1 -> chunk 2*blockIdx+sub
  const int c = blockIdx.x * 2 + sub;
  __shared__ int bad;
  if (tid == 0) bad = 0;
  __syncthreads();

  const float L1 = lam1[f], L2 = lam2[f];
  const float An = 2.0f - L2;          // negative-branch center
  {
    bool b = (fabsf(L1) < F_EPS) || (fabsf(An) < F_EPS);
#pragma unroll
    for (int j = 1; j < 6; ++j) {
      float dp = 0.1f * rp[f * 10 + 2 * (j - 1)];
      float dn = -0.1f * rp[f * 10 + 2 * (j - 1) + 1];
      b = b || (fabsf(L1 + dp) < F_EPS) || (fabsf(An + dn) < F_EPS)
            || (fabsf(dp) > DELTA_MAX) || (fabsf(dn) > DELTA_MAX);
    }
    if (b) bad = 1;  // benign same-value race
  }
  __syncthreads();

  const float* xp = x + (size_t)c * rpt * NFEAT + f;
  float out[NSLOT];

  if (bad == 0) {
    // ---- moment path: plain loop, TLP hides latency ----
    float Mp[6], Mp2[6], Mn[6], Mn2[6];
#pragma unroll
    for (int k = 0; k < 6; ++k) { Mp[k] = 0.f; Mp2[k] = 0.f; Mn[k] = 0.f; Mn2[k] = 0.f; }
    float u2p = 0.f, u2a = 0.f, npos = 0.f;

#pragma unroll 4
    for (int i = 0; i < rpt; ++i) {
      const float v = xp[(size_t)i * NFEAT];
      const bool pos = v >= 0.0f;
      const float u = FAST_LOG2(1.0f + fabsf(v));
      u2a += u;
      u2p += pos ? u : 0.0f;
      npos += pos ? 1.0f : 0.0f;
      const float q = u * F_LN2;
      const float B = FAST_EXP2((pos ? L1 : An) * u);
      const float B2 = B * B;
      const float Bp = pos ? B : 0.0f;
      const float Bn = B - Bp;
      const float Cp = pos ? B2 : 0.0f;
      const float Cn = B2 - Cp;
      Mp[0] += Bp; Mp2[0] += Cp; Mn[0] += Bn; Mn2[0] += Cn;
      float qk = q;
      Mp[1] = fmaf(Bp, qk, Mp[1]); Mp2[1] = fmaf(Cp, qk, Mp2[1]);
      Mn[1] = fmaf(Bn, qk, Mn[1]); Mn2[1] = fmaf(Cn, qk, Mn2[1]);
#pragma unroll
      for (int k = 2; k < 6; ++k) {
        qk *= q;
        Mp[k] = fmaf(Bp, qk, Mp[k]); Mp2[k] = fmaf(Cp, qk, Mp2[k]);
        Mn[k] = fmaf(Bn, qk, Mn[k]); Mn2[k] = fmaf(Cn, qk, Mn2[k]);
      }
    }
#pragma unroll
    for (int k = 0; k < 6; ++k) {
      out[k]      = Mp[k];
      out[6 + k]  = Mp2[k];
      out[12 + k] = Mn[k];
      out[18 + k] = Mn2[k];
    }
    out[24] = u2p; out[25] = u2a; out[26] = npos; out[27] = 0.0f;
  } else {
    // ---- exact general path: direct sums (flag=1) ----
    float ga_p[6], ga_n[6], gs_p[6], gs_n[6], gt_p[6], gt_n[6];
#pragma unroll
    for (int j = 0; j < 6; ++j) {
      float dp = (j == 0) ? 0.0f : 0.1f * rp[f * 10 + 2 * (j - 1)];
      float dn = (j == 0) ? 0.0f : -0.1f * rp[f * 10 + 2 * (j - 1) + 1];
      float a1 = L1 + dp;
      float a2 = An + dn;
      bool z1 = fabsf(a1) < F_EPS;
      bool z2 = fabsf(a2) < F_EPS;
      ga_p[j] = z1 ? 0.0f : a1;
      gs_p[j] = z1 ? 0.0f : 1.0f / a1;
      gt_p[j] = z1 ? F_LN2 : 0.0f;
      ga_n[j] = z2 ? 0.0f : a2;
      gs_n[j] = z2 ? 0.0f : -1.0f / a2;
      gt_n[j] = z2 ? -F_LN2 : 0.0f;
    }
    float as[6], aq[6];
#pragma unroll
    for (int j = 0; j < 6; ++j) { as[j] = 0.f; aq[j] = 0.f; }
    float u2p = 0.f, u2a = 0.f;
    for (int i = 0; i < rpt; ++i) {
      float v = xp[(size_t)i * NFEAT];
      bool pos = v >= 0.0f;
      float u2 = FAST_LOG2(1.0f + fabsf(v));
      u2a += u2;
      u2p += pos ? u2 : 0.0f;
#pragma unroll
      for (int j = 0; j < 6; ++j) {
        float a  = pos ? ga_p[j] : ga_n[j];
        float s  = pos ? gs_p[j] : gs_n[j];
        float tt = pos ? gt_p[j] : gt_n[j];
        float e = FAST_EXP2(a * u2);
        float y = fmaf(tt, u2, fmaf(s, e, -s));
        as[j] += y;
        aq[j] = fmaf(y, y, aq[j]);
      }
    }
#pragma unroll
    for (int k = 0; k < NSLOT; ++k) out[k] = 0.0f;
#pragma unroll
    for (int j = 0; j < 6; ++j) { out[j] = as[j]; out[6 + j] = aq[j]; }
    out[24] = u2p; out[25] = u2a; out[26] = 0.0f; out[27] = 1.0f;
  }

#pragma unroll
  for (int k = 0; k < NSLOT; ++k)
    P1[((size_t)c * NSLOT + k) * NFEAT + f] = out[k];
}

// Stage A reduce: block (k, cg): S2[(k*RGRP+cg)*NFEAT+f] = sum over c-subrange.
__global__ __launch_bounds__(256) void k_reduce_S(
    const float* __restrict__ P1, double* __restrict__ S2, int CHv)
{
  const int k = blockIdx.x / RGRP;
  const int cg = blockIdx.x % RGRP;
  const int f = threadIdx.x;
  const int per = CHv / RGRP;
  const int c0 = cg * per;
  double a0 = 0.0, a1 = 0.0, a2 = 0.0, a3 = 0.0;
  for (int c = c0; c < c0 + per; c += 4) {
    a0 += (double)P1[((size_t)(c + 0) * NSLOT + k) * NFEAT + f];
    a1 += (double)P1[((size_t)(c + 1) * NSLOT + k) * NFEAT + f];
    a2 += (double)P1[((size_t)(c + 2) * NSLOT + k) * NFEAT + f];
    a3 += (double)P1[((size_t)(c + 3) * NSLOT + k) * NFEAT + f];
  }
  S2[((size_t)k * RGRP + cg) * NFEAT + f] = (a0 + a1) + (a2 + a3);
}

// One thread per feature: reconstruct 6 scores in f64, min, tie-average.
__global__ __launch_bounds__(256) void k_pick(
    const double* __restrict__ S2, const float* __restrict__ lam1,
    const float* __restrict__ lam2, const float* __restrict__ rp,
    float* __restrict__ bestL, int* __restrict__ tied,
    double* __restrict__ bitsF, int* __restrict__ anyTied)
{
  const int f = threadIdx.x;
  if (f == 0) *anyTied = 0;
  double s[NSLOT];
#pragma unroll
  for (int k = 0; k < NSLOT; ++k) {
    double a = 0.0;
#pragma unroll
    for (int cg = 0; cg < RGRP; ++cg)
      a += S2[((size_t)k * RGRP + cg) * NFEAT + f];
    s[k] = a;
  }
  const double n = (double)NROWS;
  const bool direct = s[27] > 0.5;
  const double npos = s[26];
  const double nneg = n - npos;
  const double sup = s[24];
  const double sun = s[25] - s[24];
  const float L1 = lam1[f], L2 = lam2[f];
  const double dAn = 2.0 - (double)L2;   // f64 negative-branch center
  double scores[6], al1[6], al2[6];
#pragma unroll
  for (int j = 0; j < 6; ++j) {
    float l1 = (j == 0) ? L1 : L1 + 0.1f * rp[f * 10 + 2 * (j - 1)];
    float l2 = (j == 0) ? L2 : L2 + 0.1f * rp[f * 10 + 2 * (j - 1) + 1];
    al1[j] = (double)l1; al2[j] = (double)l2;
    bool z1 = fabsf(l1) < F_EPS;
    bool z2 = fabsf(l2 - 2.0f) < F_EPS;
    double ccp = z1 ? -1.0 : (double)l1 - 1.0;
    double ccn = z2 ? -1.0 : 1.0 - (double)l2;
    double ljb = ccp * sup + ccn * sun;

    double sum_y, sum_y2;
    if (direct) {
      sum_y  = s[j];
      sum_y2 = s[6 + j];
    } else {
      const double dp  = (double)l1 - (double)L1;
      const double dnn = (2.0 - (double)l2) - dAn;
      const double sp = 1.0 / ((double)L1 + dp);
      const double sn = -1.0 / (dAn + dnn);
      const double Ep  = horner_exp(&s[0],  dp);
      const double Ep2 = horner_exp(&s[6],  2.0 * dp);
      const double En  = horner_exp(&s[12], dnn);
      const double En2 = horner_exp(&s[18], 2.0 * dnn);
      sum_y  = sp * (Ep - npos) + sn * (En - nneg);
      sum_y2 = sp * sp * (Ep2 - 2.0 * Ep + npos)
             + sn * sn * (En2 - 2.0 * En + nneg);
    }
    double mean = sum_y / n;
    double var = sum_y2 / n - mean * mean;
    var = var > 1e-12 ? var : 1e-12;
    scores[j] = n * (D_HALF_LOG2_2PIE + 0.5 * log2(var)) + ljb + D_LAMBDA_BITS;
  }
  double mn = scores[0];
#pragma unroll
  for (int j = 1; j < 6; ++j) mn = scores[j] < mn ? scores[j] : mn;
  double wsum = 0.0, b1 = 0.0, b2 = 0.0;
#pragma unroll
  for (int j = 0; j < 6; ++j) {
    double w = (scores[j] == mn) ? 1.0 : 0.0;
    wsum += w; b1 += w * al1[j]; b2 += w * al2[j];
  }
  bestL[2 * f]     = (float)(b1 / wsum);
  bestL[2 * f + 1] = (float)(b2 / wsum);
  const int isTied = (wsum > 1.5) ? 1 : 0;
  tied[f] = isTied;
  if (isTied) atomicOr(anyTied, 1);
  bitsF[f] = mn;   // unique min: identical to re-evaluating at best lambda
}

// Fallback pass 2 (only if some feature tied: averaged lambda is new).
__global__ __launch_bounds__(256) void k_pass2(
    const float* __restrict__ x, const float* __restrict__ bestL,
    const int* __restrict__ anyTied, float* __restrict__ P2)
{
  if (*anyTied == 0) return;
  const int t = threadIdx.x;
  const int c = blockIdx.x;
  const int rpt = NROWS / CH2;   // 128
  const float l1 = bestL[2 * t], l2 = bestL[2 * t + 1];
  const bool z1 = fabsf(l1) < F_EPS;
  const bool z2 = fabsf(l2 - 2.0f) < F_EPS;
  const float tm = 2.0f - l2;
  const float a_p = z1 ? 0.f : l1,  s_pv = z1 ? 0.f : 1.f / l1,  t_pv = z1 ? F_LN2 : 0.f;
  const float a_n = z2 ? 0.f : tm,  s_nv = z2 ? 0.f : -1.f / tm, t_nv = z2 ? -F_LN2 : 0.f;

  float sy = 0.f, sq = 0.f;
  const float* xp = x + (size_t)c * rpt * NFEAT + t;
  for (int i = 0; i < rpt; ++i) {
    float v = xp[(size_t)i * NFEAT];
    bool pos = v >= 0.0f;
    float u2 = FAST_LOG2(1.0f + fabsf(v));
    float a  = pos ? a_p : a_n;
    float s  = pos ? s_pv : s_nv;
    float tt = pos ? t_pv : t_nv;
    float e = FAST_EXP2(a * u2);
    float y = fmaf(tt, u2, fmaf(s, e, -s));
    sy += y;
    sq = fmaf(y, y, sq);
  }
  P2[((size_t)c * 2 + 0) * NFEAT + t] = sy;
  P2[((size_t)c * 2 + 1) * NFEAT + t] = sq;
}

__global__ __launch_bounds__(64) void k_featbits(
    const float* __restrict__ P1, const float* __restrict__ P2,
    const float* __restrict__ bestL, const int* __restrict__ tied,
    double* __restrict__ bitsF, int CHv)
{
  const int f = blockIdx.x;
  if (!tied[f]) return;
  const int lane = threadIdx.x;
  double s0 = 0.0, s1 = 0.0, sup = 0.0, sua = 0.0;
  for (int c = lane; c < CH2; c += 64) {
    s0 += (double)P2[((size_t)c * 2 + 0) * NFEAT + f];
    s1 += (double)P2[((size_t)c * 2 + 1) * NFEAT + f];
  }
  for (int c = lane; c < CHv; c += 64) {
    sup += (double)P1[((size_t)c * NSLOT + 24) * NFEAT + f];
    sua += (double)P1[((size_t)c * NSLOT + 25) * NFEAT + f];
  }
  s0 = wave_reduce_add(s0); s1 = wave_reduce_add(s1);
  sup = wave_reduce_add(sup); sua = wave_reduce_add(sua);
  if (lane == 0) {
    const float l1 = bestL[2 * f], l2 = bestL[2 * f + 1];
    bool z1 = fabsf(l1) < F_EPS;
    bool z2 = fabsf(l2 - 2.0f) < F_EPS;
    double ccp = z1 ? -1.0 : (double)l1 - 1.0;
    double ccn = z2 ? -1.0 : 1.0 - (double)l2;
    double ljb = ccp * sup + ccn * (sua - sup);
    const double n = (double)NROWS;
    double mean = s0 / n;
    double var = s1 / n - mean * mean;
    var = var > 1e-12 ? var : 1e-12;
    bitsF[f] = n * (D_HALF_LOG2_2PIE + 0.5 * log2(var)) + ljb + D_LAMBDA_BITS;
  }
}

__global__ __launch_bounds__(256) void k_final(
    const double* __restrict__ bitsF, const double* __restrict__ pSums,
    float* __restrict__ out)
{
  __shared__ double l[4];
  double s = bitsF[threadIdx.x];
  s = wave_reduce_add(s);
  int w = threadIdx.x >> 6;
  if ((threadIdx.x & 63) == 0) l[w] = s;
  __syncthreads();
  if (threadIdx.x == 0) {
    double data = l[0] + l[1] + l[2] + l[3];
    const double n = (double)PCOUNT;
    double mean = pSums[0] / n;
    double var = pSums[1] / n - mean * mean;
    var = var > 1e-12 ? var : 1e-12;
    double model = n * (D_HALF_LOG2_2PIE + 0.5 * log2(var)) + D_LAMBDA_BITS;
    out[0] = (float)(data + model);
  }
}

extern "C" void kernel_launch(void* const* d_in, const int* in_sizes, int n_in,
                              void* d_out, int out_size, void* d_ws, size_t ws_size,
                              hipStream_t stream)
{
  const float* x      = (const float*)d_in[0];
  const float* lam1   = (const float*)d_in[1];
  const float* lam2   = (const float*)d_in[2];
  const float* rp     = (const float*)d_in[3];
  const float* params = (const float*)d_in[4];

  char* ws = (char*)d_ws;
  double* pSums  = (double*)ws;                 // 16 B   -> 16
  float*  bestL  = (float*)(ws + 16);           // 2048   -> 2064
  double* bitsF  = (double*)(ws + 2064);        // 2048   -> 4112
  int*    tied   = (int*)(ws + 4112);           // 1024   -> 5136
  int*    anyT   = (int*)(ws + 5136);           // 4      -> pad 5152
  double* S2     = (double*)(ws + 5152);        // 28*16*256*8 = 917504 -> 922656
  float*  P1     = (float*)(ws + 922656);

  // chunk count: CHv=1024 (even, 512 YJ blocks of 512 thr), fall back if ws small
  int CHv = 1024;
  while (CHv > 128) {
    size_t need = 922656 + (size_t)CHv * NSLOT * NFEAT * 4
                         + (size_t)CH2 * 2 * NFEAT * 4;
    if (need <= ws_size) break;
    CHv >>= 1;
  }
  float* P2 = (float*)(ws + 922656 + (size_t)CHv * NSLOT * NFEAT * 4);
  int rpt = NROWS / CHv;   // 64 at CHv=1024

  (void)hipMemsetAsync(pSums, 0, 16, stream);
  k_pass1<<<CHv / 2 + PBLK, 512, 0, stream>>>(x, lam1, lam2, rp, params, P1,
                                              pSums, CHv, rpt);
  k_reduce_S<<<NSLOT * RGRP, 256, 0, stream>>>(P1, S2, CHv);
  k_pick<<<1, 256, 0, stream>>>(S2, lam1, lam2, rp, bestL, tied, bitsF, anyT);
  k_pass2<<<CH2, 256, 0, stream>>>(x, bestL, anyT, P2);
  k_featbits<<<NFEAT, 64, 0, stream>>>(P1, P2, bestL, tied, bitsF, CHv);
  k_final<<<1, 256, 0, stream>>>(bitsF, pSums, (float*)d_out);
}

// Round 26
// 59.122 us; speedup vs baseline: 1.1984x; 1.1984x over previous
//
#include <hip/hip_runtime.h>
#include <math.h>

#define NFEAT 256
#define NROWS 65536
#define PCOUNT 4194304
#define PBLK 64                      // param-reduce blocks appended to pass1 grid
#define CH2 512                      // pass2 fallback chunks
#define RGRP 4                       // reduce_S set-groups
#define NSLOT 28                     // P1 slots per set per feature
#define F_EPS 5.9604645e-07f         // float32 eps * 5
#define F_LN2 0.69314718056f
#define DELTA_MAX 0.45f              // poly-validity gate on |0.1*rp|

#define FAST_LOG2(v) __builtin_log2f(v)   // v_log_f32
#define FAST_EXP2(v) __builtin_exp2f(v)   // v_exp_f32

constexpr double D_HALF_LOG2_2PIE = 0.5 * 2.8378770664093453 / 0.6931471805599453;
constexpr double D_LAMBDA_BITS = 13.287712379549449; // 2*log2(100)

__device__ inline double wave_reduce_add(double v) {
  for (int o = 32; o > 0; o >>= 1) v += __shfl_down(v, o, 64);
  return v;
}

// sum_k d^k/k! * m[k], k=0..5 (Horner)
__device__ inline double horner_exp(const double* m, double d) {
  double p = m[5] * (1.0 / 120.0);
  p = p * d + m[4] * (1.0 / 24.0);
  p = p * d + m[3] * (1.0 / 6.0);
  p = p * d + m[2] * 0.5;
  p = p * d + m[1];
  p = p * d + m[0];
  return p;
}

// ---------------------------------------------------------------------------
// Pass 1 (moment form, dual-chunk 512-thr blocks + end LDS merge):
// thread = (f=tid&255, sub=tid>>8); sub processes chunk 2*blockIdx+sub; at
// the END the two subs' 28 outputs are merged via one LDS pass + barrier ->
// P1 holds NSETS = nyj sets (HALF of r25's traffic; reduce_S reads halve).
// Moments: M_k = sum B*q^k, M2_k = sum B^2*q^k (k=0..5, pos/neg);
// B = exp2(center*u), q = u*ln2, u = log2(1+|x|). Reconstruction per-feature
// in f64 in k_pick (5th-order Taylor, same truncation as r13 -> absmax 0.0).
// Slots: 0..5 Mp, 6..11 Mp2, 12..17 Mn, 18..23 Mn2, 24 u2p, 25 u2a,
// 26 npos, 27 flag (>0 = direct sums from exact general path).
// Blocks >= nyj: parameter tensor partials -> pPart (no atomics, no memset).
// ---------------------------------------------------------------------------
__global__ __launch_bounds__(512, 8) void k_pass1(
    const float* __restrict__ x, const float* __restrict__ lam1,
    const float* __restrict__ lam2, const float* __restrict__ rp,
    const float* __restrict__ params, float* __restrict__ P1,
    double* __restrict__ pPart, int nyj, int rpt)
{
  const int tid = threadIdx.x;

  if ((int)blockIdx.x >= nyj) {
    // ---- parameter tensor partials: one pair per block, no atomics ----
    __shared__ double lred[2][8];
    const int b = blockIdx.x - nyj;
    const float4* p4 = (const float4*)params;
    double s = 0.0, q = 0.0;
    for (int i = b * 512 + tid; i < PCOUNT / 4; i += PBLK * 512) {
      float4 v = p4[i];
      s += (double)v.x + (double)v.y + (double)v.z + (double)v.w;
      q += (double)v.x * v.x + (double)v.y * v.y
         + (double)v.z * v.z + (double)v.w * v.w;
    }
    s = wave_reduce_add(s); q = wave_reduce_add(q);
    const int w = tid >> 6;
    if ((tid & 63) == 0) { lred[0][w] = s; lred[1][w] = q; }
    __syncthreads();
    if (tid == 0) {
      double S = 0.0, Q = 0.0;
#pragma unroll
      for (int i = 0; i < 8; ++i) { S += lred[0][i]; Q += lred[1][i]; }
      pPart[2 * b]     = S;
      pPart[2 * b + 1] = Q;
    }
    return;
  }

  const int f = tid & 255;
  const int sub = tid >> 8;            // 0/1 -> chunk 2*blockIdx+sub
  const int c = blockIdx.x * 2 + sub;
  __shared__ float red[NSLOT][NFEAT];  // 28 KB end-merge buffer
  __shared__ int bad;
  if (tid == 0) bad = 0;
  __syncthreads();

  const float L1 = lam1[f], L2 = lam2[f];
  const float An = 2.0f - L2;          // negative-branch center
  {
    bool b = (fabsf(L1) < F_EPS) || (fabsf(An) < F_EPS);
#pragma unroll
    for (int j = 1; j < 6; ++j) {
      float dp = 0.1f * rp[f * 10 + 2 * (j - 1)];
      float dn = -0.1f * rp[f * 10 + 2 * (j - 1) + 1];
      b = b || (fabsf(L1 + dp) < F_EPS) || (fabsf(An + dn) < F_EPS)
            || (fabsf(dp) > DELTA_MAX) || (fabsf(dn) > DELTA_MAX);
    }
    if (b) bad = 1;  // benign same-value race
  }
  __syncthreads();

  const float* xp = x + (size_t)c * rpt * NFEAT + f;
  float out[NSLOT];

  if (bad == 0) {
    // ---- moment path: plain loop, TLP hides latency ----
    float Mp[6], Mp2[6], Mn[6], Mn2[6];
#pragma unroll
    for (int k = 0; k < 6; ++k) { Mp[k] = 0.f; Mp2[k] = 0.f; Mn[k] = 0.f; Mn2[k] = 0.f; }
    float u2p = 0.f, u2a = 0.f, npos = 0.f;

#pragma unroll 4
    for (int i = 0; i < rpt; ++i) {
      const float v = xp[(size_t)i * NFEAT];
      const bool pos = v >= 0.0f;
      const float u = FAST_LOG2(1.0f + fabsf(v));
      u2a += u;
      u2p += pos ? u : 0.0f;
      npos += pos ? 1.0f : 0.0f;
      const float q = u * F_LN2;
      const float B = FAST_EXP2((pos ? L1 : An) * u);
      const float B2 = B * B;
      const float Bp = pos ? B : 0.0f;
      const float Bn = B - Bp;
      const float Cp = pos ? B2 : 0.0f;
      const float Cn = B2 - Cp;
      Mp[0] += Bp; Mp2[0] += Cp; Mn[0] += Bn; Mn2[0] += Cn;
      float qk = q;
      Mp[1] = fmaf(Bp, qk, Mp[1]); Mp2[1] = fmaf(Cp, qk, Mp2[1]);
      Mn[1] = fmaf(Bn, qk, Mn[1]); Mn2[1] = fmaf(Cn, qk, Mn2[1]);
#pragma unroll
      for (int k = 2; k < 6; ++k) {
        qk *= q;
        Mp[k] = fmaf(Bp, qk, Mp[k]); Mp2[k] = fmaf(Cp, qk, Mp2[k]);
        Mn[k] = fmaf(Bn, qk, Mn[k]); Mn2[k] = fmaf(Cn, qk, Mn2[k]);
      }
    }
#pragma unroll
    for (int k = 0; k < 6; ++k) {
      out[k]      = Mp[k];
      out[6 + k]  = Mp2[k];
      out[12 + k] = Mn[k];
      out[18 + k] = Mn2[k];
    }
    out[24] = u2p; out[25] = u2a; out[26] = npos; out[27] = 0.0f;
  } else {
    // ---- exact general path: direct sums (flag>0) ----
    float ga_p[6], ga_n[6], gs_p[6], gs_n[6], gt_p[6], gt_n[6];
#pragma unroll
    for (int j = 0; j < 6; ++j) {
      float dp = (j == 0) ? 0.0f : 0.1f * rp[f * 10 + 2 * (j - 1)];
      float dn = (j == 0) ? 0.0f : -0.1f * rp[f * 10 + 2 * (j - 1) + 1];
      float a1 = L1 + dp;
      float a2 = An + dn;
      bool z1 = fabsf(a1) < F_EPS;
      bool z2 = fabsf(a2) < F_EPS;
      ga_p[j] = z1 ? 0.0f : a1;
      gs_p[j] = z1 ? 0.0f : 1.0f / a1;
      gt_p[j] = z1 ? F_LN2 : 0.0f;
      ga_n[j] = z2 ? 0.0f : a2;
      gs_n[j] = z2 ? 0.0f : -1.0f / a2;
      gt_n[j] = z2 ? -F_LN2 : 0.0f;
    }
    float as[6], aq[6];
#pragma unroll
    for (int j = 0; j < 6; ++j) { as[j] = 0.f; aq[j] = 0.f; }
    float u2p = 0.f, u2a = 0.f;
    for (int i = 0; i < rpt; ++i) {
      float v = xp[(size_t)i * NFEAT];
      bool pos = v >= 0.0f;
      float u2 = FAST_LOG2(1.0f + fabsf(v));
      u2a += u2;
      u2p += pos ? u2 : 0.0f;
#pragma unroll
      for (int j = 0; j < 6; ++j) {
        float a  = pos ? ga_p[j] : ga_n[j];
        float s  = pos ? gs_p[j] : gs_n[j];
        float tt = pos ? gt_p[j] : gt_n[j];
        float e = FAST_EXP2(a * u2);
        float y = fmaf(tt, u2, fmaf(s, e, -s));
        as[j] += y;
        aq[j] = fmaf(y, y, aq[j]);
      }
    }
#pragma unroll
    for (int k = 0; k < NSLOT; ++k) out[k] = 0.0f;
#pragma unroll
    for (int j = 0; j < 6; ++j) { out[j] = as[j]; out[6 + j] = aq[j]; }
    out[24] = u2p; out[25] = u2a; out[26] = 0.0f; out[27] = 1.0f;
  }

  // ---- end merge: sub1 -> LDS, sub0 adds and writes set = blockIdx ----
  if (sub == 1) {
#pragma unroll
    for (int k = 0; k < NSLOT; ++k) red[k][f] = out[k];
  }
  __syncthreads();
  if (sub == 0) {
#pragma unroll
    for (int k = 0; k < NSLOT; ++k)
      P1[((size_t)blockIdx.x * NSLOT + k) * NFEAT + f] = out[k] + red[k][f];
  }
}

// Stage A reduce: block (k, cg): S2[(k*RGRP+cg)*NFEAT+f] = sum over set-range.
__global__ __launch_bounds__(256) void k_reduce_S(
    const float* __restrict__ P1, double* __restrict__ S2, int nsets)
{
  const int k = blockIdx.x / RGRP;
  const int cg = blockIdx.x % RGRP;
  const int f = threadIdx.x;
  const int per = nsets / RGRP;
  const int c0 = cg * per;
  double a0 = 0.0, a1 = 0.0, a2 = 0.0, a3 = 0.0;
  for (int c = c0; c < c0 + per; c += 4) {
    a0 += (double)P1[((size_t)(c + 0) * NSLOT + k) * NFEAT + f];
    a1 += (double)P1[((size_t)(c + 1) * NSLOT + k) * NFEAT + f];
    a2 += (double)P1[((size_t)(c + 2) * NSLOT + k) * NFEAT + f];
    a3 += (double)P1[((size_t)(c + 3) * NSLOT + k) * NFEAT + f];
  }
  S2[((size_t)k * RGRP + cg) * NFEAT + f] = (a0 + a1) + (a2 + a3);
}

// One thread per feature: reconstruct 6 scores in f64, min, tie-average.
__global__ __launch_bounds__(256) void k_pick(
    const double* __restrict__ S2, const float* __restrict__ lam1,
    const float* __restrict__ lam2, const float* __restrict__ rp,
    float* __restrict__ bestL, int* __restrict__ tied,
    double* __restrict__ bitsF, int* __restrict__ anyTied)
{
  const int f = threadIdx.x;
  if (f == 0) *anyTied = 0;
  double s[NSLOT];
#pragma unroll
  for (int k = 0; k < NSLOT; ++k) {
    double a = 0.0;
#pragma unroll
    for (int cg = 0; cg < RGRP; ++cg)
      a += S2[((size_t)k * RGRP + cg) * NFEAT + f];
    s[k] = a;
  }
  const double n = (double)NROWS;
  const bool direct = s[27] > 0.5;
  const double npos = s[26];
  const double nneg = n - npos;
  const double sup = s[24];
  const double sun = s[25] - s[24];
  const float L1 = lam1[f], L2 = lam2[f];
  const double dAn = 2.0 - (double)L2;   // f64 negative-branch center
  double scores[6], al1[6], al2[6];
#pragma unroll
  for (int j = 0; j < 6; ++j) {
    float l1 = (j == 0) ? L1 : L1 + 0.1f * rp[f * 10 + 2 * (j - 1)];
    float l2 = (j == 0) ? L2 : L2 + 0.1f * rp[f * 10 + 2 * (j - 1) + 1];
    al1[j] = (double)l1; al2[j] = (double)l2;
    bool z1 = fabsf(l1) < F_EPS;
    bool z2 = fabsf(l2 - 2.0f) < F_EPS;
    double ccp = z1 ? -1.0 : (double)l1 - 1.0;
    double ccn = z2 ? -1.0 : 1.0 - (double)l2;
    double ljb = ccp * sup + ccn * sun;

    double sum_y, sum_y2;
    if (direct) {
      sum_y  = s[j];
      sum_y2 = s[6 + j];
    } else {
      const double dp  = (double)l1 - (double)L1;
      const double dnn = (2.0 - (double)l2) - dAn;
      const double sp = 1.0 / ((double)L1 + dp);
      const double sn = -1.0 / (dAn + dnn);
      const double Ep  = horner_exp(&s[0],  dp);
      const double Ep2 = horner_exp(&s[6],  2.0 * dp);
      const double En  = horner_exp(&s[12], dnn);
      const double En2 = horner_exp(&s[18], 2.0 * dnn);
      sum_y  = sp * (Ep - npos) + sn * (En - nneg);
      sum_y2 = sp * sp * (Ep2 - 2.0 * Ep + npos)
             + sn * sn * (En2 - 2.0 * En + nneg);
    }
    double mean = sum_y / n;
    double var = sum_y2 / n - mean * mean;
    var = var > 1e-12 ? var : 1e-12;
    scores[j] = n * (D_HALF_LOG2_2PIE + 0.5 * log2(var)) + ljb + D_LAMBDA_BITS;
  }
  double mn = scores[0];
#pragma unroll
  for (int j = 1; j < 6; ++j) mn = scores[j] < mn ? scores[j] : mn;
  double wsum = 0.0, b1 = 0.0, b2 = 0.0;
#pragma unroll
  for (int j = 0; j < 6; ++j) {
    double w = (scores[j] == mn) ? 1.0 : 0.0;
    wsum += w; b1 += w * al1[j]; b2 += w * al2[j];
  }
  bestL[2 * f]     = (float)(b1 / wsum);
  bestL[2 * f + 1] = (float)(b2 / wsum);
  const int isTied = (wsum > 1.5) ? 1 : 0;
  tied[f] = isTied;
  if (isTied) atomicOr(anyTied, 1);
  bitsF[f] = mn;   // unique min: identical to re-evaluating at best lambda
}

// Fallback pass 2 (only if some feature tied: averaged lambda is new).
__global__ __launch_bounds__(256) void k_pass2(
    const float* __restrict__ x, const float* __restrict__ bestL,
    const int* __restrict__ anyTied, float* __restrict__ P2)
{
  if (*anyTied == 0) return;
  const int t = threadIdx.x;
  const int c = blockIdx.x;
  const int rpt = NROWS / CH2;   // 128
  const float l1 = bestL[2 * t], l2 = bestL[2 * t + 1];
  const bool z1 = fabsf(l1) < F_EPS;
  const bool z2 = fabsf(l2 - 2.0f) < F_EPS;
  const float tm = 2.0f - l2;
  const float a_p = z1 ? 0.f : l1,  s_pv = z1 ? 0.f : 1.f / l1,  t_pv = z1 ? F_LN2 : 0.f;
  const float a_n = z2 ? 0.f : tm,  s_nv = z2 ? 0.f : -1.f / tm, t_nv = z2 ? -F_LN2 : 0.f;

  float sy = 0.f, sq = 0.f;
  const float* xp = x + (size_t)c * rpt * NFEAT + t;
  for (int i = 0; i < rpt; ++i) {
    float v = xp[(size_t)i * NFEAT];
    bool pos = v >= 0.0f;
    float u2 = FAST_LOG2(1.0f + fabsf(v));
    float a  = pos ? a_p : a_n;
    float s  = pos ? s_pv : s_nv;
    float tt = pos ? t_pv : t_nv;
    float e = FAST_EXP2(a * u2);
    float y = fmaf(tt, u2, fmaf(s, e, -s));
    sy += y;
    sq = fmaf(y, y, sq);
  }
  P2[((size_t)c * 2 + 0) * NFEAT + t] = sy;
  P2[((size_t)c * 2 + 1) * NFEAT + t] = sq;
}

__global__ __launch_bounds__(64) void k_featbits(
    const float* __restrict__ P1, const float* __restrict__ P2,
    const float* __restrict__ bestL, const int* __restrict__ tied,
    double* __restrict__ bitsF, int nsets)
{
  const int f = blockIdx.x;
  if (!tied[f]) return;
  const int lane = threadIdx.x;
  double s0 = 0.0, s1 = 0.0, sup = 0.0, sua = 0.0;
  for (int c = lane; c < CH2; c += 64) {
    s0 += (double)P2[((size_t)c * 2 + 0) * NFEAT + f];
    s1 += (double)P2[((size_t)c * 2 + 1) * NFEAT + f];
  }
  for (int c = lane; c < nsets; c += 64) {
    sup += (double)P1[((size_t)c * NSLOT + 24) * NFEAT + f];
    sua += (double)P1[((size_t)c * NSLOT + 25) * NFEAT + f];
  }
  s0 = wave_reduce_add(s0); s1 = wave_reduce_add(s1);
  sup = wave_reduce_add(sup); sua = wave_reduce_add(sua);
  if (lane == 0) {
    const float l1 = bestL[2 * f], l2 = bestL[2 * f + 1];
    bool z1 = fabsf(l1) < F_EPS;
    bool z2 = fabsf(l2 - 2.0f) < F_EPS;
    double ccp = z1 ? -1.0 : (double)l1 - 1.0;
    double ccn = z2 ? -1.0 : 1.0 - (double)l2;
    double ljb = ccp * sup + ccn * (sua - sup);
    const double n = (double)NROWS;
    double mean = s0 / n;
    double var = s1 / n - mean * mean;
    var = var > 1e-12 ? var : 1e-12;
    bitsF[f] = n * (D_HALF_LOG2_2PIE + 0.5 * log2(var)) + ljb + D_LAMBDA_BITS;
  }
}

__global__ __launch_bounds__(256) void k_final(
    const double* __restrict__ bitsF, const double* __restrict__ pPart,
    float* __restrict__ out)
{
  __shared__ double l[4], lp[4], lq[4];
  const int t = threadIdx.x;
  double s  = bitsF[t];
  double sp = (t < PBLK) ? pPart[2 * t]     : 0.0;
  double sq = (t < PBLK) ? pPart[2 * t + 1] : 0.0;
  s = wave_reduce_add(s); sp = wave_reduce_add(sp); sq = wave_reduce_add(sq);
  const int w = t >> 6;
  if ((t & 63) == 0) { l[w] = s; lp[w] = sp; lq[w] = sq; }
  __syncthreads();
  if (t == 0) {
    double data = l[0] + l[1] + l[2] + l[3];
    double S = lp[0] + lp[1] + lp[2] + lp[3];
    double Q = lq[0] + lq[1] + lq[2] + lq[3];
    const double n = (double)PCOUNT;
    double mean = S / n;
    double var = Q / n - mean * mean;
    var = var > 1e-12 ? var : 1e-12;
    double model = n * (D_HALF_LOG2_2PIE + 0.5 * log2(var)) + D_LAMBDA_BITS;
    out[0] = (float)(data + model);
  }
}

extern "C" void kernel_launch(void* const* d_in, const int* in_sizes, int n_in,
                              void* d_out, int out_size, void* d_ws, size_t ws_size,
                              hipStream_t stream)
{
  const float* x      = (const float*)d_in[0];
  const float* lam1   = (const float*)d_in[1];
  const float* lam2   = (const float*)d_in[2];
  const float* rp     = (const float*)d_in[3];
  const float* params = (const float*)d_in[4];

  char* ws = (char*)d_ws;
  double* pPart = (double*)ws;                  // 64*2*8 = 1024 -> 1024
  float*  bestL = (float*)(ws + 1024);          // 2048   -> 3072
  double* bitsF = (double*)(ws + 3072);         // 2048   -> 5120
  int*    tied  = (int*)(ws + 5120);            // 1024   -> 6144
  int*    anyT  = (int*)(ws + 6144);            // 4      -> pad 6176
  double* S2    = (double*)(ws + 6176);         // 28*4*256*8 = 229376 -> 235552
  float*  P1    = (float*)(ws + 235552);

  // sets: prefer 512 (1024 chunks merged 2:1), fall back if ws small
  int nsets = 512;
  while (nsets > 64) {
    size_t need = 235552 + (size_t)nsets * NSLOT * NFEAT * 4
                         + (size_t)CH2 * 2 * NFEAT * 4;
    if (need <= ws_size) break;
    nsets >>= 1;
  }
  float* P2 = (float*)(ws + 235552 + (size_t)nsets * NSLOT * NFEAT * 4);
  int rpt = NROWS / (2 * nsets);   // 64 at nsets=512

  k_pass1<<<nsets + PBLK, 512, 0, stream>>>(x, lam1, lam2, rp, params, P1,
                                            pPart, nsets, rpt);
  k_reduce_S<<<NSLOT * RGRP, 256, 0, stream>>>(P1, S2, nsets);
  k_pick<<<1, 256, 0, stream>>>(S2, lam1, lam2, rp, bestL, tied, bitsF, anyT);
  k_pass2<<<CH2, 256, 0, stream>>>(x, bestL, anyT, P2);
  k_featbits<<<NFEAT, 64, 0, stream>>>(P1, P2, bestL, tied, bitsF, nsets);
  k_final<<<1, 256, 0, stream>>>(bitsF, pPart, (float*)d_out);
}